// Round 8
// baseline (287.857 us; speedup 1.0000x reference)
//
#include <hip/hip_runtime.h>

// Problem constants (from reference setup_inputs)
constexpr int NN = 50000;   // nodes
constexpr int H  = 128;     // hidden
constexpr int F  = 256;     // input features
constexpr int C  = 40;      // classes

// graph-prepass partitioning: 8 ranges of 6400 nodes, 32 chunks, 1024-thread
// hist/fill blocks. hist linear ids 0..255: id%8 = range => XCD pinning.
constexpr int RSZ = 6400;
constexpr int NRG = 8;
constexpr int CHP = 32;     // partial chunks (merge chain length)
constexpr int GBK = (NN + 63) / 64;   // 782 GEMM row-blocks

typedef short bf16x8 __attribute__((ext_vector_type(8)));
typedef float f32x4  __attribute__((ext_vector_type(4)));

__device__ inline unsigned short f2bf(float f) {          // RNE fp32 -> bf16
    unsigned u = __float_as_uint(f);
    u += 0x7fff + ((u >> 16) & 1);
    return (unsigned short)(u >> 16);
}
__device__ inline float bf2f(unsigned short s) {
    return __uint_as_float(((unsigned)s) << 16);
}

// async global->LDS DMA, 16B per lane: per-lane GLOBAL address (gather-capable),
// wave-uniform LDS base + implicit lane*16 dest. Validated on this problem in
// the GEMM staging path (rounds 2-4, passed).
__device__ __forceinline__ void gll16(const unsigned short* g, void* l) {
    __builtin_amdgcn_global_load_lds(
        (const __attribute__((address_space(1))) void*)g,
        (__attribute__((address_space(3))) void*)l, 16, 0, 0);
}

// ------------------------------------------------ GEMM body (shared device fn)
// Skinny GEMM (N<=128, K<=256): B is L2-resident -> NO LDS, NO barriers.
//   A plane chunk(rb,t,k4,row) = ((rb*NK+t)*4+k4)*64+row, 8 bf16 each
//   B plane chunk(t,k4,col)    = (t*4+k4)*BN+col
// MODE 1: oh = row-major bf16(acc*row_scale)  (feeds aggregate)
// MODE 2: oh/ol = hi/lo split of (acc + bias) in A-plane layout keyed NK'=4
template<int MODE, int BN, int NK>
__device__ __forceinline__ void gemm_body(
        int by,
        const unsigned short* __restrict__ Ah, const unsigned short* __restrict__ Al,
        const unsigned short* __restrict__ Bh, const unsigned short* __restrict__ Bl,
        const float* __restrict__ bias, const float* __restrict__ row_scale,
        unsigned short* __restrict__ oh, unsigned short* __restrict__ ol,
        int M, int Nout) {
    constexpr int NT = BN / 64;

    const int tid  = threadIdx.x;
    const int wave = tid >> 6;
    const int lane = tid & 63;
    const int quad = lane >> 4;
    const int lr   = lane & 15;
    const int row0 = by * 64;
    const int wn0  = wave * (BN / 4);

    f32x4 acc[4][NT];
#pragma unroll
    for (int mt = 0; mt < 4; mt++)
#pragma unroll
        for (int nt = 0; nt < NT; nt++)
            acc[mt][nt] = (f32x4){0.f, 0.f, 0.f, 0.f};

    // per-lane element offsets (in ushort units)
    const unsigned short* aH = Ah + ((long)by * NK) * 2048 + (quad * 64 + lr) * 8;
    const unsigned short* aL = Al + ((long)by * NK) * 2048 + (quad * 64 + lr) * 8;
    const unsigned short* bH = Bh + (quad * BN + wn0 + lr) * 8;
    const unsigned short* bL = Bl + (quad * BN + wn0 + lr) * 8;

#pragma unroll
    for (int t = 0; t < NK; t++) {
        bf16x8 ah[4], av[4], bh[NT], bv[NT];
#pragma unroll
        for (int mt = 0; mt < 4; mt++) {
            ah[mt] = *(const bf16x8*)&aH[t * 2048 + mt * 128];   // mt*16 rows * 8
            av[mt] = *(const bf16x8*)&aL[t * 2048 + mt * 128];
        }
#pragma unroll
        for (int nt = 0; nt < NT; nt++) {
            bh[nt] = *(const bf16x8*)&bH[t * 4 * BN * 8 + nt * 128];
            bv[nt] = *(const bf16x8*)&bL[t * 4 * BN * 8 + nt * 128];
        }
#pragma unroll
        for (int mt = 0; mt < 4; mt++)
#pragma unroll
            for (int nt = 0; nt < NT; nt++) {
                acc[mt][nt] = __builtin_amdgcn_mfma_f32_16x16x32_bf16(ah[mt], bh[nt], acc[mt][nt], 0, 0, 0);
                acc[mt][nt] = __builtin_amdgcn_mfma_f32_16x16x32_bf16(av[mt], bh[nt], acc[mt][nt], 0, 0, 0);
                acc[mt][nt] = __builtin_amdgcn_mfma_f32_16x16x32_bf16(ah[mt], bv[nt], acc[mt][nt], 0, 0, 0);
            }
    }

#pragma unroll
    for (int mt = 0; mt < 4; mt++) {
#pragma unroll
        for (int nt = 0; nt < NT; nt++) {
            const int gc = wn0 + nt * 16 + lr;
#pragma unroll
            for (int r = 0; r < 4; r++) {
                const int gr = row0 + mt * 16 + quad * 4 + r;
                float v = acc[mt][nt][r];
                if (MODE == 1) {
                    if (gr < M) oh[(long)gr * 128 + gc] = f2bf(v * row_scale[gr]);
                } else {
                    float x = v + bias[gc];     // pad rows: A-planes are zeroed -> x=bias, harmless
                    unsigned short hh = f2bf(x);
                    unsigned short ll = f2bf(x - bf2f(hh));
                    long idx = ((((long)by * 4 + (gc >> 5)) * 4 + ((gc >> 3) & 3)) * 64
                                + (mt * 16 + quad * 4 + r)) * 8 + (gc & 7);
                    oh[idx] = hh;
                    ol[idx] = ll;
                }
            }
        }
    }
}

// ------------------------------------------------ D1: hist (256) + wprep (72) + A-split (782)
__global__ __launch_bounds__(1024) void hist_prep(
        const int* __restrict__ src, const int* __restrict__ dst,
        unsigned short* __restrict__ p_out, unsigned short* __restrict__ p_in, int E,
        const float* __restrict__ Wp, const float* __restrict__ W1,
        const float* __restrict__ W2, const float* __restrict__ Wc,
        unsigned short* __restrict__ ph, unsigned short* __restrict__ pl,
        unsigned short* __restrict__ h1h, unsigned short* __restrict__ h1l,
        unsigned short* __restrict__ h2h, unsigned short* __restrict__ h2l,
        unsigned short* __restrict__ chh, unsigned short* __restrict__ cll,
        const float* __restrict__ nf,
        unsigned short* __restrict__ nfh, unsigned short* __restrict__ nfl) {
    __shared__ int ho[RSZ];
    __shared__ int hd[RSZ];
    const int t = threadIdx.x;
    if (blockIdx.x < NRG * CHP) {
        const int r = blockIdx.x & 7;        // linear id = r + 8*b (XCD pinning)
        const int b = blockIdx.x >> 3;
        for (int i = t; i < RSZ; i += 1024) { ho[i] = 0; hd[i] = 0; }
        __syncthreads();
        const int base = r * RSZ;
        const int CE = (E + CHP - 1) / CHP;
        const int e0 = b * CE, e1 = min(E, e0 + CE);
#pragma unroll 4
        for (int e = e0 + t; e < e1; e += 1024) {
            int s = src[e], d = dst[e];
            unsigned so = (unsigned)(s - base);
            unsigned dof = (unsigned)(d - base);
            if (so < (unsigned)RSZ) atomicAdd(&ho[so], 1);
            if (dof < (unsigned)RSZ) atomicAdd(&hd[dof], 1);
        }
        __syncthreads();
        const long po = ((long)r * CHP + b) * RSZ;   // even
        unsigned* o32 = (unsigned*)&p_out[po];
        unsigned* i32 = (unsigned*)&p_in[po];
        for (int i = t; i < RSZ / 2; i += 1024) {
            o32[i] = (unsigned)ho[2 * i] | ((unsigned)ho[2 * i + 1] << 16);
            i32[i] = (unsigned)hd[2 * i] | ((unsigned)hd[2 * i + 1] << 16);
        }
        return;
    }
    if (blockIdx.x < NRG * CHP + 72) {
        // weight transpose + hi/lo split -> DMA layout (73728 = 72*1024 elems)
        int i = (blockIdx.x - NRG * CHP) * 1024 + t;
        const float* W; unsigned short *Bh, *Bl; int K, N, Np, j;
        if (i < 32768)        { W = Wp; Bh = ph;  Bl = pl;  K = 256; N = 128; Np = 128; j = i; }
        else if (i < 49152)   { W = W1; Bh = h1h; Bl = h1l; K = 128; N = 128; Np = 128; j = i - 32768; }
        else if (i < 65536)   { W = W2; Bh = h2h; Bl = h2l; K = 128; N = 128; Np = 128; j = i - 49152; }
        else if (i < 73728)   { W = Wc; Bh = chh; Bl = cll; K = 128; N = 40;  Np = 64;  j = i - 65536; }
        else return;
        int n = j / K, k = j % K;
        float v = (n < N) ? W[(long)k * N + n] : 0.f;
        unsigned short hh = f2bf(v);
        unsigned short ll = f2bf(v - bf2f(hh));
        long di = (((long)(k >> 5) * 4 + ((k >> 3) & 3)) * Np + n) * 8 + (k & 7);
        Bh[di] = hh;
        Bl[di] = ll;
        return;
    }
    // ---- A-split: rb-th 64-row block of n_feats -> nfh/nfl planes (NK=8)
    // streaming: no LDS, no barriers, all 1024 threads active.
    const int rb   = blockIdx.x - (NRG * CHP + 72);
    const int k4   = t & 3;
    const int row  = (t >> 2) & 63;
    const int tq   = t >> 8;                 // 0..3
    const int grow = rb * 64 + row;
    const float* rp = &nf[(long)grow * F];
#pragma unroll
    for (int hh2 = 0; hh2 < 2; hh2++) {
        const int tt = tq * 2 + hh2;         // k-step 0..7
        float4 v0 = make_float4(0.f, 0.f, 0.f, 0.f);
        float4 v1 = make_float4(0.f, 0.f, 0.f, 0.f);
        if (grow < NN) {
            v0 = *(const float4*)&rp[tt * 32 + k4 * 8];
            v1 = *(const float4*)&rp[tt * 32 + k4 * 8 + 4];
        }
        unsigned short a0 = f2bf(v0.x), a1 = f2bf(v0.y), a2 = f2bf(v0.z), a3 = f2bf(v0.w);
        unsigned short a4 = f2bf(v1.x), a5 = f2bf(v1.y), a6 = f2bf(v1.z), a7 = f2bf(v1.w);
        unsigned short b0 = f2bf(v0.x - bf2f(a0)), b1 = f2bf(v0.y - bf2f(a1));
        unsigned short b2 = f2bf(v0.z - bf2f(a2)), b3 = f2bf(v0.w - bf2f(a3));
        unsigned short b4 = f2bf(v1.x - bf2f(a4)), b5 = f2bf(v1.y - bf2f(a5));
        unsigned short b6 = f2bf(v1.z - bf2f(a6)), b7 = f2bf(v1.w - bf2f(a7));
        uint4 hv, lv;
        hv.x = (unsigned)a0 | ((unsigned)a1 << 16);
        hv.y = (unsigned)a2 | ((unsigned)a3 << 16);
        hv.z = (unsigned)a4 | ((unsigned)a5 << 16);
        hv.w = (unsigned)a6 | ((unsigned)a7 << 16);
        lv.x = (unsigned)b0 | ((unsigned)b1 << 16);
        lv.y = (unsigned)b2 | ((unsigned)b3 << 16);
        lv.z = (unsigned)b4 | ((unsigned)b5 << 16);
        lv.w = (unsigned)b6 | ((unsigned)b7 << 16);
        const long base = ((((long)rb * 8 + tt) * 4 + k4) * 64 + row) * 8;
        *(uint4*)&nfh[base] = hv;
        *(uint4*)&nfl[base] = lv;
    }
}

// ------------------------------------------------ D2: merge_scan (196) + proj GEMM (782)
__global__ __launch_bounds__(256) void merge_proj(
        const unsigned short* __restrict__ p_out, unsigned short* __restrict__ p_in,
        int* __restrict__ cnt_in, float* __restrict__ rs_out, float* __restrict__ rs_in,
        int* __restrict__ row_start, int* __restrict__ block_sums, int n, int nb,
        const unsigned short* __restrict__ Ah, const unsigned short* __restrict__ Al,
        const unsigned short* __restrict__ Bh, const unsigned short* __restrict__ Bl,
        const float* __restrict__ bias,
        unsigned short* __restrict__ xh, unsigned short* __restrict__ xl, int M) {
    if ((int)blockIdx.x < nb) {
        __shared__ int sh[256];
        const int t = threadIdx.x;
        const int i = blockIdx.x * 256 + t;
        int si = 0;
        if (i < n) {
            const int r = i / RSZ, off = i % RSZ;
            const long pb = (long)r * CHP * RSZ + off;
            int so = 0;
#pragma unroll 8
            for (int b = 0; b < CHP; b++) {
                so += p_out[pb + (long)b * RSZ];
                int v = p_in[pb + (long)b * RSZ];
                p_in[pb + (long)b * RSZ] = (unsigned short)si;
                si += v;
            }
            cnt_in[i] = si;
            rs_out[i] = rsqrtf((float)max(so, 1));
            rs_in[i]  = rsqrtf((float)max(si, 1));
        }
        sh[t] = si;
        __syncthreads();
#pragma unroll
        for (int off = 1; off < 256; off <<= 1) {
            int u = (t >= off) ? sh[t - off] : 0;
            __syncthreads();
            sh[t] += u;
            __syncthreads();
        }
        if (i < n) row_start[i] = sh[t] - si;
        if (t == 255) block_sums[blockIdx.x] = sh[255];
        return;
    }
    gemm_body<2, 128, 8>(blockIdx.x - nb, Ah, Al, Bh, Bl, bias, nullptr,
                         xh, xl, M, 128);
}

// ------------------------------------------------ D3: scan_sums (1) + layer1 GEMM (782)
__global__ __launch_bounds__(256) void scansums_gemm(
        int* __restrict__ block_sums, int nb,
        const unsigned short* __restrict__ Ah, const unsigned short* __restrict__ Al,
        const unsigned short* __restrict__ Bh, const unsigned short* __restrict__ Bl,
        const float* __restrict__ row_scale, unsigned short* __restrict__ outh, int M) {
    if (blockIdx.x == 0) {
        __shared__ int sh[256];
        const int t = threadIdx.x;
        const int v = (t < nb) ? block_sums[t] : 0;
        sh[t] = v;
        __syncthreads();
#pragma unroll
        for (int off = 1; off < 256; off <<= 1) {
            int u = (t >= off) ? sh[t - off] : 0;
            __syncthreads();
            sh[t] += u;
            __syncthreads();
        }
        if (t < nb) block_sums[t] = sh[t] - v;
        return;
    }
    gemm_body<1, 128, 4>(blockIdx.x - 1, Ah, Al, Bh, Bl, nullptr, row_scale,
                         outh, nullptr, M, 128);
}

// ------------------------------------------------ D4: CSR fill, 1024 threads
__global__ __launch_bounds__(1024) void fill_csr_part(
        const int* __restrict__ src, const int* __restrict__ dst,
        const int* __restrict__ row_start, const int* __restrict__ block_sums,
        const unsigned short* __restrict__ p_in,
        int* __restrict__ csr_src, int E, int n_nodes) {
    __shared__ int cur[RSZ];
    const int r = blockIdx.x;
    const int b = blockIdx.y;
    const int base = r * RSZ;
    const long po = ((long)r * CHP + b) * RSZ;
    for (int i = threadIdx.x; i < RSZ; i += 1024) {
        int node = base + i;
        int rs = (node < n_nodes) ? (row_start[node] + block_sums[node >> 8]) : 0;
        cur[i] = rs + (int)p_in[po + i];
    }
    __syncthreads();
    const int CE = (E + CHP - 1) / CHP;
    const int e0 = b * CE, e1 = min(E, e0 + CE);
#pragma unroll 8
    for (int e = e0 + threadIdx.x; e < e1; e += 1024) {
        int d = dst[e];
        unsigned dof = (unsigned)(d - base);
        if (dof < (unsigned)RSZ) {
            int pos = atomicAdd(&cur[dof], 1);   // LDS atomic
            csr_src[pos] = src[e];
        }
    }
}

// ---------------------------------------------------------------- fused aggregate+GEMM
// Block = 16 nodes. Phase 1 gather rewritten as DMA-gather: per node, burst of
// up to 16 rows via global_load_lds (per-lane GATHER addresses, wave-uniform LDS
// base) -> one vmcnt(0) drain -> conflict-free ds_read consume. Rationale: three
// register-side MLP variants all landed at 43-44us (r5/r7); Little's-law from
// the counters says ~30 outstanding lines/CU -> L1 miss-queue-bound. The DMA
// path bypasses the L1/VGPR return path. Accumulation ORDER preserved exactly
// (ascending neighbor units) -> numerics identical.
// CMODE 1: oh[gr*128+gc] = bf16(acc*rs_out[gr])   (layer-2, W2)
// CMODE 0: outf[gr*40+gc] = acc + bias2[gc]       (classifier, Wc)
template<int CMODE>
__global__ __launch_bounds__(256) void agg_gemm(
        const uint4* __restrict__ h4, const int* __restrict__ csr_src,
        const int* __restrict__ row_start, const int* __restrict__ block_sums,
        const int* __restrict__ cnt_in, const float* __restrict__ rs_in,
        const float* __restrict__ abias,
        const unsigned short* __restrict__ Bh, const unsigned short* __restrict__ Bl,
        const float* __restrict__ rs_out, const float* __restrict__ bias2,
        unsigned short* __restrict__ oh, float* __restrict__ outf) {
    constexpr int BN = (CMODE == 1) ? 128 : 64;
    constexpr int NT = BN / 64;
    constexpr int NP = (CMODE == 1) ? 128 : 64;
    __shared__ unsigned short Ash[16 * 136];
    __shared__ unsigned short Asl[16 * 136];
    __shared__ uint4 gbuf[4][4][4][16];   // [wave][unit][grp-row][sl] = 16KB

    const int tid  = threadIdx.x;
    const int wave = tid >> 6;
    const int lane = tid & 63;
    const int grp  = lane >> 4;        // 0..3 = neighbor slot
    const int sl   = lane & 15;        // uint4 index in row

    // hoisted per-node metadata (wave-uniform; independent loads up front)
    int s0v[4], cntv[4];
#pragma unroll
    for (int j = 0; j < 4; j++) {
        const int v = blockIdx.x * 16 + j * 4 + wave;
        s0v[j]  = row_start[v] + block_sums[v >> 8];
        cntv[j] = cnt_in[v];
    }

    // ---- phase 1: aggregate (4 nodes per wave, interleaved local rows)
    for (int j = 0; j < 4; j++) {
        const int l = j * 4 + wave;              // local row 0..15
        const int v = blockIdx.x * 16 + l;       // always < NN (3125*16)
        const int s0  = s0v[j];
        const int cnt = cntv[j];

        float ax0 = 0.f, ay0 = 0.f, ax1 = 0.f, ay1 = 0.f;
        float ax2 = 0.f, ay2 = 0.f, ax3 = 0.f, ay3 = 0.f;

        for (int nb0 = 0; nb0 < cnt; nb0 += 16) {        // burst of <=16 rows
            const int nrows = min(cnt - nb0, 16);
            // retire prior ds_reads of gbuf before DMA overwrites (different
            // counters: lgkm vs vm -- hardware does not order them)
            asm volatile("s_waitcnt lgkmcnt(0)" ::: "memory");
            __builtin_amdgcn_sched_barrier(0);
            // preload (clamped) indices -- one wait covers all 4
            int sidx[4];
#pragma unroll
            for (int d = 0; d < 4; d++) {
                if (d * 4 < nrows) {
                    int i = nb0 + d * 4 + grp;
                    sidx[d] = csr_src[(i < cnt) ? (s0 + i) : s0];
                }
            }
            // burst-issue DMA gathers: one instr = 4 scattered 256B rows
#pragma unroll
            for (int d = 0; d < 4; d++) {
                if (d * 4 < nrows)
                    gll16((const unsigned short*)&h4[(long)sidx[d] * 16 + sl],
                          &gbuf[wave][d][0][0]);
            }
            asm volatile("s_waitcnt vmcnt(0)" ::: "memory");
            __builtin_amdgcn_sched_barrier(0);
            // consume in ascending unit order (preserves old accumulation order)
#pragma unroll
            for (int d = 0; d < 4; d++) {
                if (nb0 + d * 4 + grp < cnt) {
                    uint4 u = gbuf[wave][d][grp][sl];
                    ax0 += __uint_as_float(u.x << 16); ay0 += __uint_as_float(u.x & 0xffff0000u);
                    ax1 += __uint_as_float(u.y << 16); ay1 += __uint_as_float(u.y & 0xffff0000u);
                    ax2 += __uint_as_float(u.z << 16); ay2 += __uint_as_float(u.z & 0xffff0000u);
                    ax3 += __uint_as_float(u.w << 16); ay3 += __uint_as_float(u.w & 0xffff0000u);
                }
            }
        }
        // sum across the 4 lane-groups (bits 4,5 of lane)
        ax0 += __shfl_xor(ax0, 16); ay0 += __shfl_xor(ay0, 16);
        ax1 += __shfl_xor(ax1, 16); ay1 += __shfl_xor(ay1, 16);
        ax2 += __shfl_xor(ax2, 16); ay2 += __shfl_xor(ay2, 16);
        ax3 += __shfl_xor(ax3, 16); ay3 += __shfl_xor(ay3, 16);
        ax0 += __shfl_xor(ax0, 32); ay0 += __shfl_xor(ay0, 32);
        ax1 += __shfl_xor(ax1, 32); ay1 += __shfl_xor(ay1, 32);
        ax2 += __shfl_xor(ax2, 32); ay2 += __shfl_xor(ay2, 32);
        ax3 += __shfl_xor(ax3, 32); ay3 += __shfl_xor(ay3, 32);

        if (grp == 0) {                          // lanes 0..15: cols sl*8..sl*8+7
            const float rs = rs_in[v];
            const float2 b0 = ((const float2*)abias)[sl * 4 + 0];
            const float2 b1 = ((const float2*)abias)[sl * 4 + 1];
            const float2 b2 = ((const float2*)abias)[sl * 4 + 2];
            const float2 b3 = ((const float2*)abias)[sl * 4 + 3];
            float w0 = fmaxf(ax0 * rs + b0.x, 0.f), w1 = fmaxf(ay0 * rs + b0.y, 0.f);
            float w2 = fmaxf(ax1 * rs + b1.x, 0.f), w3 = fmaxf(ay1 * rs + b1.y, 0.f);
            float w4 = fmaxf(ax2 * rs + b2.x, 0.f), w5 = fmaxf(ay2 * rs + b2.y, 0.f);
            float w6 = fmaxf(ax3 * rs + b3.x, 0.f), w7 = fmaxf(ay3 * rs + b3.y, 0.f);
            unsigned short h0 = f2bf(w0), h1 = f2bf(w1), h2 = f2bf(w2), h3 = f2bf(w3);
            unsigned short h4v = f2bf(w4), h5 = f2bf(w5), h6 = f2bf(w6), h7 = f2bf(w7);
            uint4 hv, lv;
            hv.x = (unsigned)h0 | ((unsigned)h1 << 16);
            hv.y = (unsigned)h2 | ((unsigned)h3 << 16);
            hv.z = (unsigned)h4v | ((unsigned)h5 << 16);
            hv.w = (unsigned)h6 | ((unsigned)h7 << 16);
            unsigned short l0 = f2bf(w0 - bf2f(h0)), l1 = f2bf(w1 - bf2f(h1));
            unsigned short l2 = f2bf(w2 - bf2f(h2)), l3 = f2bf(w3 - bf2f(h3));
            unsigned short l4 = f2bf(w4 - bf2f(h4v)), l5 = f2bf(w5 - bf2f(h5));
            unsigned short l6 = f2bf(w6 - bf2f(h6)), l7 = f2bf(w7 - bf2f(h7));
            lv.x = (unsigned)l0 | ((unsigned)l1 << 16);
            lv.y = (unsigned)l2 | ((unsigned)l3 << 16);
            lv.z = (unsigned)l4 | ((unsigned)l5 << 16);
            lv.w = (unsigned)l6 | ((unsigned)l7 << 16);
            *(uint4*)&Ash[l * 136 + sl * 8] = hv;
            *(uint4*)&Asl[l * 136 + sl * 8] = lv;
        }
    }
    __syncthreads();

    // ---- phase 2: GEMM 16 x BN, K=128; A from LDS, B planes from L2
    const int quad = grp;
    const int lr   = sl;
    const int wn0  = wave * (BN / 4);
    f32x4 acc[NT];
#pragma unroll
    for (int nt = 0; nt < NT; nt++) acc[nt] = (f32x4){0.f, 0.f, 0.f, 0.f};

#pragma unroll
    for (int t = 0; t < 4; t++) {
        bf16x8 ah = *(const bf16x8*)&Ash[lr * 136 + t * 32 + quad * 8];
        bf16x8 av = *(const bf16x8*)&Asl[lr * 136 + t * 32 + quad * 8];
        bf16x8 bh[NT], bv[NT];
#pragma unroll
        for (int nt = 0; nt < NT; nt++) {
            long off = ((long)(t * 4 + quad) * NP + wn0 + nt * 16 + lr) * 8;
            bh[nt] = *(const bf16x8*)&Bh[off];
            bv[nt] = *(const bf16x8*)&Bl[off];
        }
#pragma unroll
        for (int nt = 0; nt < NT; nt++) {
            acc[nt] = __builtin_amdgcn_mfma_f32_16x16x32_bf16(ah, bh[nt], acc[nt], 0, 0, 0);
            acc[nt] = __builtin_amdgcn_mfma_f32_16x16x32_bf16(av, bh[nt], acc[nt], 0, 0, 0);
            acc[nt] = __builtin_amdgcn_mfma_f32_16x16x32_bf16(ah, bv[nt], acc[nt], 0, 0, 0);
        }
    }

#pragma unroll
    for (int nt = 0; nt < NT; nt++) {
        const int gc = wn0 + nt * 16 + lr;
#pragma unroll
        for (int r = 0; r < 4; r++) {
            const int gr = blockIdx.x * 16 + quad * 4 + r;
            if (CMODE == 1) {
                oh[(long)gr * 128 + gc] = f2bf(acc[nt][r] * rs_out[gr]);
            } else {
                if (gc < C) outf[(long)gr * C + gc] = acc[nt][r] + bias2[gc];
            }
        }
    }
}

// ---------------------------------------------------------------- launch
extern "C" void kernel_launch(void* const* d_in, const int* in_sizes, int n_in,
                              void* d_out, int out_size, void* d_ws, size_t ws_size,
                              hipStream_t stream) {
    const float* n_feats = (const float*)d_in[0];
    const int*   src     = (const int*)d_in[1];
    const int*   dst     = (const int*)d_in[2];
    const float* Wp      = (const float*)d_in[3];
    const float* bp      = (const float*)d_in[4];
    const float* W1      = (const float*)d_in[5];
    const float* b1      = (const float*)d_in[6];
    const float* W2      = (const float*)d_in[7];
    const float* b2      = (const float*)d_in[8];
    const float* Wc      = (const float*)d_in[9];
    const float* bc      = (const float*)d_in[10];
    float* out = (float*)d_out;
    const int E = in_sizes[1];

    const long PSZ = (long)NRG * CHP * RSZ;    // partials: 1,638,400 u16 (3.28 MB)
    const long XPL = (long)GBK * 4 * 2048;     // x-plane elems (K=128 layout)
    const long NPL = (long)GBK * 8 * 2048;     // n_feats-plane elems (K=256 layout)

    // workspace layout (~115 MB of 256 MiB)
    char* ws = (char*)d_ws;
    unsigned short* hbuf  = (unsigned short*)ws;                    // NN*H bf16
    unsigned short* xh    = hbuf + (long)NN * H;                    // XPL
    unsigned short* xl    = xh + XPL;
    unsigned short* nfh   = xl + XPL;                               // NPL
    unsigned short* nfl   = nfh + NPL;
    unsigned short* bt_ph = nfl + NPL;                              // 8*4*128*8
    unsigned short* bt_pl = bt_ph + 32768;
    unsigned short* bt_1h = bt_pl + 32768;                          // 4*4*128*8
    unsigned short* bt_1l = bt_1h + 16384;
    unsigned short* bt_2h = bt_1l + 16384;
    unsigned short* bt_2l = bt_2h + 16384;
    unsigned short* bt_ch = bt_2l + 16384;                          // 4*4*64*8
    unsigned short* bt_cl = bt_ch + 8192;
    int*   cnt_in     = (int*)(bt_cl + 8192);                       // N
    int*   row_start  = cnt_in + NN;                                // N (within-block excl)
    float* rs_out     = (float*)(row_start + NN);                   // N
    float* rs_in      = rs_out + NN;                                // N
    int*   block_sums = (int*)(rs_in + NN);                         // 256
    unsigned short* p_out = (unsigned short*)(block_sums + 256);    // PSZ u16
    unsigned short* p_in  = p_out + PSZ;                            // PSZ u16
    int*   csr_src    = (int*)(p_in + PSZ);                         // E
    unsigned short* hbuf2 = (unsigned short*)(csr_src + E);         // NN*H bf16

    const int NB = (NN + 255) / 256;    // 196
    const int AB = NN / 16;             // 3125 fused agg+GEMM blocks

    // D1: histograms (256, XCD-pinned) + weight prep (72) + n_feats split (782)
    hist_prep<<<NRG * CHP + 72 + GBK, 1024, 0, stream>>>(
        src, dst, p_out, p_in, E, Wp, W1, W2, Wc,
        bt_ph, bt_pl, bt_1h, bt_1l, bt_2h, bt_2l, bt_ch, bt_cl,
        n_feats, nfh, nfl);
    // D2: merge+scan (196) + proj GEMM (782): xh/xl = split(n_feats @ Wp + bp)
    merge_proj<<<NB + GBK, 256, 0, stream>>>(
        p_out, p_in, cnt_in, rs_out, rs_in, row_start, block_sums, NN, NB,
        nfh, nfl, bt_ph, bt_pl, bp, xh, xl, NN);
    // D3: scan of block sums (1) + layer-1 GEMM (782): hbuf = bf16((x@W1)*rs_out)
    scansums_gemm<<<1 + GBK, 256, 0, stream>>>(
        block_sums, NB, xh, xl, bt_1h, bt_1l, rs_out, hbuf, NN);
    // D4: CSR fill (no global atomics), 1024 threads
    fill_csr_part<<<dim3(NRG, CHP), 1024, 0, stream>>>(
        src, dst, row_start, block_sums, p_in, csr_src, E, NN);
    // D5: fused aggregate-1 + layer-2 GEMM: hbuf2 = bf16((relu(rs_in*(A hbuf)+b1) @ W2)*rs_out)
    agg_gemm<1><<<AB, 256, 0, stream>>>(
        (const uint4*)hbuf, csr_src, row_start, block_sums, cnt_in, rs_in, b1,
        bt_2h, bt_2l, rs_out, nullptr, hbuf2, nullptr);
    // D6: fused aggregate-2 + classifier: out = relu(rs_in*(A hbuf2)+b2) @ Wc + bc
    agg_gemm<0><<<AB, 256, 0, stream>>>(
        (const uint4*)hbuf2, csr_src, row_start, block_sums, cnt_in, rs_in, b2,
        bt_ch, bt_cl, nullptr, bc, nullptr, out);
}

// Round 9
// 244.087 us; speedup vs baseline: 1.1793x; 1.1793x over previous
//
#include <hip/hip_runtime.h>

// Problem constants (from reference setup_inputs)
constexpr int NN = 50000;   // nodes
constexpr int H  = 128;     // hidden
constexpr int F  = 256;     // input features
constexpr int C  = 40;      // classes

// graph-prepass partitioning: 8 ranges of 6400 nodes, 32 chunks, 1024-thread
// hist/fill blocks. hist linear ids 0..255: id%8 = range => XCD pinning.
constexpr int RSZ = 6400;
constexpr int NRG = 8;
constexpr int CHP = 32;     // partial chunks (merge chain length)
constexpr int GBK = (NN + 63) / 64;   // 782 GEMM row-blocks

typedef short bf16x8 __attribute__((ext_vector_type(8)));
typedef float f32x4  __attribute__((ext_vector_type(4)));

__device__ inline unsigned short f2bf(float f) {          // RNE fp32 -> bf16
    unsigned u = __float_as_uint(f);
    u += 0x7fff + ((u >> 16) & 1);
    return (unsigned short)(u >> 16);
}
__device__ inline float bf2f(unsigned short s) {
    return __uint_as_float(((unsigned)s) << 16);
}

// ------------------------------------------------ D1: hist (256) + wprep (72) + A-split (782)
// 1024 threads. Partials chunk-major u16. A-split: pure streaming, no LDS, no
// barriers, all 1024 threads: tid -> (k4=tid&3, row=(tid>>2)&63, t=tid>>8).
__global__ __launch_bounds__(1024) void hist_prep(
        const int* __restrict__ src, const int* __restrict__ dst,
        unsigned short* __restrict__ p_out, unsigned short* __restrict__ p_in, int E,
        const float* __restrict__ Wp, const float* __restrict__ W1,
        const float* __restrict__ W2, const float* __restrict__ Wc,
        unsigned short* __restrict__ ph, unsigned short* __restrict__ pl,
        unsigned short* __restrict__ h1h, unsigned short* __restrict__ h1l,
        unsigned short* __restrict__ h2h, unsigned short* __restrict__ h2l,
        unsigned short* __restrict__ chh, unsigned short* __restrict__ cll,
        const float* __restrict__ nf,
        unsigned short* __restrict__ nfh, unsigned short* __restrict__ nfl) {
    __shared__ int ho[RSZ];
    __shared__ int hd[RSZ];
    const int t = threadIdx.x;
    if (blockIdx.x < NRG * CHP) {
        const int r = blockIdx.x & 7;        // linear id = r + 8*b (XCD pinning)
        const int b = blockIdx.x >> 3;
        for (int i = t; i < RSZ; i += 1024) { ho[i] = 0; hd[i] = 0; }
        __syncthreads();
        const int base = r * RSZ;
        const int CE = (E + CHP - 1) / CHP;
        const int e0 = b * CE, e1 = min(E, e0 + CE);
#pragma unroll 4
        for (int e = e0 + t; e < e1; e += 1024) {
            int s = src[e], d = dst[e];
            unsigned so = (unsigned)(s - base);
            unsigned dof = (unsigned)(d - base);
            if (so < (unsigned)RSZ) atomicAdd(&ho[so], 1);
            if (dof < (unsigned)RSZ) atomicAdd(&hd[dof], 1);
        }
        __syncthreads();
        const long po = ((long)r * CHP + b) * RSZ;   // even
        unsigned* o32 = (unsigned*)&p_out[po];
        unsigned* i32 = (unsigned*)&p_in[po];
        for (int i = t; i < RSZ / 2; i += 1024) {
            o32[i] = (unsigned)ho[2 * i] | ((unsigned)ho[2 * i + 1] << 16);
            i32[i] = (unsigned)hd[2 * i] | ((unsigned)hd[2 * i + 1] << 16);
        }
        return;
    }
    if (blockIdx.x < NRG * CHP + 72) {
        // weight transpose + hi/lo split -> plane layout (73728 = 72*1024 elems)
        int i = (blockIdx.x - NRG * CHP) * 1024 + t;
        const float* W; unsigned short *Bh, *Bl; int K, N, Np, j;
        if (i < 32768)        { W = Wp; Bh = ph;  Bl = pl;  K = 256; N = 128; Np = 128; j = i; }
        else if (i < 49152)   { W = W1; Bh = h1h; Bl = h1l; K = 128; N = 128; Np = 128; j = i - 32768; }
        else if (i < 65536)   { W = W2; Bh = h2h; Bl = h2l; K = 128; N = 128; Np = 128; j = i - 49152; }
        else if (i < 73728)   { W = Wc; Bh = chh; Bl = cll; K = 128; N = 40;  Np = 64;  j = i - 65536; }
        else return;
        int n = j / K, k = j % K;
        float v = (n < N) ? W[(long)k * N + n] : 0.f;
        unsigned short hh = f2bf(v);
        unsigned short ll = f2bf(v - bf2f(hh));
        long di = (((long)(k >> 5) * 4 + ((k >> 3) & 3)) * Np + n) * 8 + (k & 7);
        Bh[di] = hh;
        Bl[di] = ll;
        return;
    }
    // ---- A-split: rb-th 64-row block of n_feats -> nfh/nfl planes (NK=8)
    // streaming: no LDS, no barriers, all 1024 threads active.
    const int rb   = blockIdx.x - (NRG * CHP + 72);
    const int k4   = t & 3;
    const int row  = (t >> 2) & 63;
    const int tq   = t >> 8;                 // 0..3
    const int grow = rb * 64 + row;
    const float* rp = &nf[(long)grow * F];
#pragma unroll
    for (int hh2 = 0; hh2 < 2; hh2++) {
        const int tt = tq * 2 + hh2;         // k-step 0..7
        float4 v0 = make_float4(0.f, 0.f, 0.f, 0.f);
        float4 v1 = make_float4(0.f, 0.f, 0.f, 0.f);
        if (grow < NN) {
            v0 = *(const float4*)&rp[tt * 32 + k4 * 8];
            v1 = *(const float4*)&rp[tt * 32 + k4 * 8 + 4];
        }
        unsigned short a0 = f2bf(v0.x), a1 = f2bf(v0.y), a2 = f2bf(v0.z), a3 = f2bf(v0.w);
        unsigned short a4 = f2bf(v1.x), a5 = f2bf(v1.y), a6 = f2bf(v1.z), a7 = f2bf(v1.w);
        unsigned short b0 = f2bf(v0.x - bf2f(a0)), b1 = f2bf(v0.y - bf2f(a1));
        unsigned short b2 = f2bf(v0.z - bf2f(a2)), b3 = f2bf(v0.w - bf2f(a3));
        unsigned short b4 = f2bf(v1.x - bf2f(a4)), b5 = f2bf(v1.y - bf2f(a5));
        unsigned short b6 = f2bf(v1.z - bf2f(a6)), b7 = f2bf(v1.w - bf2f(a7));
        uint4 hv, lv;
        hv.x = (unsigned)a0 | ((unsigned)a1 << 16);
        hv.y = (unsigned)a2 | ((unsigned)a3 << 16);
        hv.z = (unsigned)a4 | ((unsigned)a5 << 16);
        hv.w = (unsigned)a6 | ((unsigned)a7 << 16);
        lv.x = (unsigned)b0 | ((unsigned)b1 << 16);
        lv.y = (unsigned)b2 | ((unsigned)b3 << 16);
        lv.z = (unsigned)b4 | ((unsigned)b5 << 16);
        lv.w = (unsigned)b6 | ((unsigned)b7 << 16);
        const long base = ((((long)rb * 8 + tt) * 4 + k4) * 64 + row) * 8;
        *(uint4*)&nfh[base] = hv;
        *(uint4*)&nfl[base] = lv;
    }
}

// ------------------------------------------------ D2: merge_scan (196) + FUSED proj+layer1 (782)
// GEMM blocks: (1) proj GEMM x = n_feats@Wp (NK=8, direct plane loads, B L2-hot);
// (2) split x+bias into padded LDS tile [64][136] (write <=4-way, read 2-way=free;
//     layout verified index-identical to the old global plane round-trip);
// (3) recompute rs_out locally from p_out (no cross-block race; same formula);
// (4) layer-1 GEMM from LDS (NK=4, B=W1 planes) -> hbuf = bf16((x@W1)*rs_out).
// Saves the 51MB xh/xl write + 51MB re-read and one dispatch. Numerics identical:
// same f2bf split values, same 3-product MFMA order, same epilogue math.
__global__ __launch_bounds__(256) void merge_proj_l1(
        const unsigned short* __restrict__ p_out, unsigned short* __restrict__ p_in,
        int* __restrict__ cnt_in, float* __restrict__ rs_out, float* __restrict__ rs_in,
        int* __restrict__ row_start, int* __restrict__ block_sums, int n, int nb,
        const unsigned short* __restrict__ Ah, const unsigned short* __restrict__ Al,
        const unsigned short* __restrict__ BPh, const unsigned short* __restrict__ BPl,
        const float* __restrict__ bp,
        const unsigned short* __restrict__ B1h, const unsigned short* __restrict__ B1l,
        unsigned short* __restrict__ hbuf, int M) {
    __shared__ unsigned short Xh[64 * 136];
    __shared__ unsigned short Xl[64 * 136];
    __shared__ float rso[64];
    if ((int)blockIdx.x < nb) {
        __shared__ int sh[256];
        const int t = threadIdx.x;
        const int i = blockIdx.x * 256 + t;
        int si = 0;
        if (i < n) {
            const int r = i / RSZ, off = i % RSZ;
            const long pb = (long)r * CHP * RSZ + off;
            int so = 0;
#pragma unroll 8
            for (int b = 0; b < CHP; b++) {
                so += p_out[pb + (long)b * RSZ];
                int v = p_in[pb + (long)b * RSZ];
                p_in[pb + (long)b * RSZ] = (unsigned short)si;
                si += v;
            }
            cnt_in[i] = si;
            rs_out[i] = rsqrtf((float)max(so, 1));
            rs_in[i]  = rsqrtf((float)max(si, 1));
        }
        sh[t] = si;
        __syncthreads();
#pragma unroll
        for (int off = 1; off < 256; off <<= 1) {
            int u = (t >= off) ? sh[t - off] : 0;
            __syncthreads();
            sh[t] += u;
            __syncthreads();
        }
        if (i < n) row_start[i] = sh[t] - si;
        if (t == 255) block_sums[blockIdx.x] = sh[255];
        return;
    }

    const int by   = blockIdx.x - nb;
    const int tid  = threadIdx.x;
    const int wave = tid >> 6;
    const int lane = tid & 63;
    const int quad = lane >> 4;
    const int lr   = lane & 15;
    const int row0 = by * 64;
    const int wn0  = wave * 32;

    // local rs_out for this block's 64 rows (independent u16 loads, L2-hot;
    // issued before the GEMM so latency hides under it)
    if (tid < 64) {
        int node = row0 + tid;
        int so = 0;
        if (node < M) {
            int rr = node / RSZ, off = node % RSZ;
            const unsigned short* pp = &p_out[(long)rr * CHP * RSZ + off];
#pragma unroll
            for (int b = 0; b < CHP; b++) so += pp[(long)b * RSZ];
        }
        rso[tid] = rsqrtf((float)max(so, 1));
    }

    // ---- proj GEMM: x = n_feats @ Wp  (NK=8, BN=128, direct loads)
    f32x4 acc[4][2];
#pragma unroll
    for (int mt = 0; mt < 4; mt++)
#pragma unroll
        for (int nt = 0; nt < 2; nt++)
            acc[mt][nt] = (f32x4){0.f, 0.f, 0.f, 0.f};

    const unsigned short* aH = Ah + ((long)by * 8) * 2048 + (quad * 64 + lr) * 8;
    const unsigned short* aL = Al + ((long)by * 8) * 2048 + (quad * 64 + lr) * 8;
    const unsigned short* bH = BPh + (quad * 128 + wn0 + lr) * 8;
    const unsigned short* bL = BPl + (quad * 128 + wn0 + lr) * 8;

#pragma unroll
    for (int t = 0; t < 8; t++) {
        bf16x8 ah[4], av[4], bh[2], bv[2];
#pragma unroll
        for (int mt = 0; mt < 4; mt++) {
            ah[mt] = *(const bf16x8*)&aH[t * 2048 + mt * 128];
            av[mt] = *(const bf16x8*)&aL[t * 2048 + mt * 128];
        }
#pragma unroll
        for (int nt = 0; nt < 2; nt++) {
            bh[nt] = *(const bf16x8*)&bH[t * 4096 + nt * 128];
            bv[nt] = *(const bf16x8*)&bL[t * 4096 + nt * 128];
        }
#pragma unroll
        for (int mt = 0; mt < 4; mt++)
#pragma unroll
            for (int nt = 0; nt < 2; nt++) {
                acc[mt][nt] = __builtin_amdgcn_mfma_f32_16x16x32_bf16(ah[mt], bh[nt], acc[mt][nt], 0, 0, 0);
                acc[mt][nt] = __builtin_amdgcn_mfma_f32_16x16x32_bf16(av[mt], bh[nt], acc[mt][nt], 0, 0, 0);
                acc[mt][nt] = __builtin_amdgcn_mfma_f32_16x16x32_bf16(ah[mt], bv[nt], acc[mt][nt], 0, 0, 0);
            }
    }

    // ---- split x+bias into LDS (identical f2bf values as old MODE-2 path)
#pragma unroll
    for (int mt = 0; mt < 4; mt++) {
#pragma unroll
        for (int nt = 0; nt < 2; nt++) {
            const int gc = wn0 + nt * 16 + lr;
            const float bb = bp[gc];
#pragma unroll
            for (int r = 0; r < 4; r++) {
                const int row = mt * 16 + quad * 4 + r;
                float x = acc[mt][nt][r] + bb;
                unsigned short hh = f2bf(x);
                unsigned short ll = f2bf(x - bf2f(hh));
                Xh[row * 136 + gc] = hh;
                Xl[row * 136 + gc] = ll;
            }
        }
    }
    __syncthreads();

    // ---- layer-1 GEMM: hbuf = bf16((x @ W1) * rs_out)  (NK=4, A from LDS)
    f32x4 a2[4][2];
#pragma unroll
    for (int mt = 0; mt < 4; mt++)
#pragma unroll
        for (int nt = 0; nt < 2; nt++)
            a2[mt][nt] = (f32x4){0.f, 0.f, 0.f, 0.f};

#pragma unroll
    for (int t = 0; t < 4; t++) {
        bf16x8 ah[4], av[4], bh[2], bv[2];
#pragma unroll
        for (int mt = 0; mt < 4; mt++) {
            ah[mt] = *(const bf16x8*)&Xh[(mt * 16 + lr) * 136 + t * 32 + quad * 8];
            av[mt] = *(const bf16x8*)&Xl[(mt * 16 + lr) * 136 + t * 32 + quad * 8];
        }
#pragma unroll
        for (int nt = 0; nt < 2; nt++) {
            long off = ((long)(t * 4 + quad) * 128 + wn0 + nt * 16 + lr) * 8;
            bh[nt] = *(const bf16x8*)&B1h[off];
            bv[nt] = *(const bf16x8*)&B1l[off];
        }
#pragma unroll
        for (int mt = 0; mt < 4; mt++)
#pragma unroll
            for (int nt = 0; nt < 2; nt++) {
                a2[mt][nt] = __builtin_amdgcn_mfma_f32_16x16x32_bf16(ah[mt], bh[nt], a2[mt][nt], 0, 0, 0);
                a2[mt][nt] = __builtin_amdgcn_mfma_f32_16x16x32_bf16(av[mt], bh[nt], a2[mt][nt], 0, 0, 0);
                a2[mt][nt] = __builtin_amdgcn_mfma_f32_16x16x32_bf16(ah[mt], bv[nt], a2[mt][nt], 0, 0, 0);
            }
    }

#pragma unroll
    for (int mt = 0; mt < 4; mt++) {
#pragma unroll
        for (int nt = 0; nt < 2; nt++) {
            const int gc = wn0 + nt * 16 + lr;
#pragma unroll
            for (int r = 0; r < 4; r++) {
                const int rl = mt * 16 + quad * 4 + r;
                const int gr = row0 + rl;
                if (gr < M) hbuf[(long)gr * 128 + gc] = f2bf(a2[mt][nt][r] * rso[rl]);
            }
        }
    }
}

// ------------------------------------------------ D3: scan of block sums (1 block)
__global__ __launch_bounds__(256) void scansums(int* __restrict__ block_sums, int nb) {
    __shared__ int sh[256];
    const int t = threadIdx.x;
    const int v = (t < nb) ? block_sums[t] : 0;
    sh[t] = v;
    __syncthreads();
#pragma unroll
    for (int off = 1; off < 256; off <<= 1) {
        int u = (t >= off) ? sh[t - off] : 0;
        __syncthreads();
        sh[t] += u;
        __syncthreads();
    }
    if (t < nb) block_sums[t] = sh[t] - v;
}

// ------------------------------------------------ D4: CSR fill, 1024 threads
__global__ __launch_bounds__(1024) void fill_csr_part(
        const int* __restrict__ src, const int* __restrict__ dst,
        const int* __restrict__ row_start, const int* __restrict__ block_sums,
        const unsigned short* __restrict__ p_in,
        int* __restrict__ csr_src, int E, int n_nodes) {
    __shared__ int cur[RSZ];
    const int r = blockIdx.x;
    const int b = blockIdx.y;
    const int base = r * RSZ;
    const long po = ((long)r * CHP + b) * RSZ;
    for (int i = threadIdx.x; i < RSZ; i += 1024) {
        int node = base + i;
        int rs = (node < n_nodes) ? (row_start[node] + block_sums[node >> 8]) : 0;
        cur[i] = rs + (int)p_in[po + i];
    }
    __syncthreads();
    const int CE = (E + CHP - 1) / CHP;
    const int e0 = b * CE, e1 = min(E, e0 + CE);
#pragma unroll 8
    for (int e = e0 + threadIdx.x; e < e1; e += 1024) {
        int d = dst[e];
        unsigned dof = (unsigned)(d - base);
        if (dof < (unsigned)RSZ) {
            int pos = atomicAdd(&cur[dof], 1);   // LDS atomic
            csr_src[pos] = src[e];
        }
    }
}

// ---------------------------------------------------------------- fused aggregate+GEMM
// ROUND-5 VERSION (best measured: 43.0us). Gather is latency x MSHR bound --
// r7 (wider MLP, 44.2) and r8 (DMA burst, 55.3) both falsified restructuring.
// Block = 16 nodes; phase 1 per-wave gather/reduce into padded LDS [16][136];
// phase 2: 16xBN GEMM K=128, A from LDS, B planes from L2.
// CMODE 1: oh[gr*128+gc] = bf16(acc*rs_out[gr])   (layer-2, W2)
// CMODE 0: outf[gr*40+gc] = acc + bias2[gc]       (classifier, Wc)
template<int CMODE>
__global__ __launch_bounds__(256) void agg_gemm(
        const uint4* __restrict__ h4, const int* __restrict__ csr_src,
        const int* __restrict__ row_start, const int* __restrict__ block_sums,
        const int* __restrict__ cnt_in, const float* __restrict__ rs_in,
        const float* __restrict__ abias,
        const unsigned short* __restrict__ Bh, const unsigned short* __restrict__ Bl,
        const float* __restrict__ rs_out, const float* __restrict__ bias2,
        unsigned short* __restrict__ oh, float* __restrict__ outf) {
    constexpr int BN = (CMODE == 1) ? 128 : 64;
    constexpr int NT = BN / 64;
    constexpr int NP = (CMODE == 1) ? 128 : 64;
    __shared__ unsigned short Ash[16 * 136];
    __shared__ unsigned short Asl[16 * 136];

    const int tid  = threadIdx.x;
    const int wave = tid >> 6;
    const int lane = tid & 63;
    const int grp  = lane >> 4;        // 0..3 = neighbor slot
    const int sl   = lane & 15;        // uint4 index in row

    // ---- phase 1: aggregate (4 nodes per wave, interleaved local rows)
    for (int j = 0; j < 4; j++) {
        const int l = j * 4 + wave;              // local row 0..15
        const int v = blockIdx.x * 16 + l;       // always < NN (3125*16)
        const int s0  = row_start[v] + block_sums[v >> 8];
        const int cnt = cnt_in[v];

        float ax0 = 0.f, ay0 = 0.f, ax1 = 0.f, ay1 = 0.f;
        float ax2 = 0.f, ay2 = 0.f, ax3 = 0.f, ay3 = 0.f;
        int i0 = 0;
        for (; i0 + 8 <= cnt; i0 += 8) {         // 8 neighbors in flight
            int sA = csr_src[s0 + i0 + grp];
            int sB = csr_src[s0 + i0 + 4 + grp];
            uint4 uA = h4[(long)sA * 16 + sl];
            uint4 uB = h4[(long)sB * 16 + sl];
            ax0 += __uint_as_float(uA.x << 16) + __uint_as_float(uB.x << 16);
            ay0 += __uint_as_float(uA.x & 0xffff0000u) + __uint_as_float(uB.x & 0xffff0000u);
            ax1 += __uint_as_float(uA.y << 16) + __uint_as_float(uB.y << 16);
            ay1 += __uint_as_float(uA.y & 0xffff0000u) + __uint_as_float(uB.y & 0xffff0000u);
            ax2 += __uint_as_float(uA.z << 16) + __uint_as_float(uB.z << 16);
            ay2 += __uint_as_float(uA.z & 0xffff0000u) + __uint_as_float(uB.z & 0xffff0000u);
            ax3 += __uint_as_float(uA.w << 16) + __uint_as_float(uB.w << 16);
            ay3 += __uint_as_float(uA.w & 0xffff0000u) + __uint_as_float(uB.w & 0xffff0000u);
        }
        for (; i0 + 4 <= cnt; i0 += 4) {
            int s = csr_src[s0 + i0 + grp];
            uint4 u = h4[(long)s * 16 + sl];
            ax0 += __uint_as_float(u.x << 16); ay0 += __uint_as_float(u.x & 0xffff0000u);
            ax1 += __uint_as_float(u.y << 16); ay1 += __uint_as_float(u.y & 0xffff0000u);
            ax2 += __uint_as_float(u.z << 16); ay2 += __uint_as_float(u.z & 0xffff0000u);
            ax3 += __uint_as_float(u.w << 16); ay3 += __uint_as_float(u.w & 0xffff0000u);
        }
        if (i0 + grp < cnt) {                    // 0..3 tail neighbors
            int s = csr_src[s0 + i0 + grp];
            uint4 u = h4[(long)s * 16 + sl];
            ax0 += __uint_as_float(u.x << 16); ay0 += __uint_as_float(u.x & 0xffff0000u);
            ax1 += __uint_as_float(u.y << 16); ay1 += __uint_as_float(u.y & 0xffff0000u);
            ax2 += __uint_as_float(u.z << 16); ay2 += __uint_as_float(u.z & 0xffff0000u);
            ax3 += __uint_as_float(u.w << 16); ay3 += __uint_as_float(u.w & 0xffff0000u);
        }
        // sum across the 4 lane-groups (bits 4,5 of lane)
        ax0 += __shfl_xor(ax0, 16); ay0 += __shfl_xor(ay0, 16);
        ax1 += __shfl_xor(ax1, 16); ay1 += __shfl_xor(ay1, 16);
        ax2 += __shfl_xor(ax2, 16); ay2 += __shfl_xor(ay2, 16);
        ax3 += __shfl_xor(ax3, 16); ay3 += __shfl_xor(ay3, 16);
        ax0 += __shfl_xor(ax0, 32); ay0 += __shfl_xor(ay0, 32);
        ax1 += __shfl_xor(ax1, 32); ay1 += __shfl_xor(ay1, 32);
        ax2 += __shfl_xor(ax2, 32); ay2 += __shfl_xor(ay2, 32);
        ax3 += __shfl_xor(ax3, 32); ay3 += __shfl_xor(ay3, 32);

        if (grp == 0) {                          // lanes 0..15: cols sl*8..sl*8+7
            const float rs = rs_in[v];
            const float2 b0 = ((const float2*)abias)[sl * 4 + 0];
            const float2 b1 = ((const float2*)abias)[sl * 4 + 1];
            const float2 b2 = ((const float2*)abias)[sl * 4 + 2];
            const float2 b3 = ((const float2*)abias)[sl * 4 + 3];
            float w0 = fmaxf(ax0 * rs + b0.x, 0.f), w1 = fmaxf(ay0 * rs + b0.y, 0.f);
            float w2 = fmaxf(ax1 * rs + b1.x, 0.f), w3 = fmaxf(ay1 * rs + b1.y, 0.f);
            float w4 = fmaxf(ax2 * rs + b2.x, 0.f), w5 = fmaxf(ay2 * rs + b2.y, 0.f);
            float w6 = fmaxf(ax3 * rs + b3.x, 0.f), w7 = fmaxf(ay3 * rs + b3.y, 0.f);
            unsigned short h0 = f2bf(w0), h1 = f2bf(w1), h2 = f2bf(w2), h3 = f2bf(w3);
            unsigned short h4v = f2bf(w4), h5 = f2bf(w5), h6 = f2bf(w6), h7 = f2bf(w7);
            uint4 hv, lv;
            hv.x = (unsigned)h0 | ((unsigned)h1 << 16);
            hv.y = (unsigned)h2 | ((unsigned)h3 << 16);
            hv.z = (unsigned)h4v | ((unsigned)h5 << 16);
            hv.w = (unsigned)h6 | ((unsigned)h7 << 16);
            unsigned short l0 = f2bf(w0 - bf2f(h0)), l1 = f2bf(w1 - bf2f(h1));
            unsigned short l2 = f2bf(w2 - bf2f(h2)), l3 = f2bf(w3 - bf2f(h3));
            unsigned short l4 = f2bf(w4 - bf2f(h4v)), l5 = f2bf(w5 - bf2f(h5));
            unsigned short l6 = f2bf(w6 - bf2f(h6)), l7 = f2bf(w7 - bf2f(h7));
            lv.x = (unsigned)l0 | ((unsigned)l1 << 16);
            lv.y = (unsigned)l2 | ((unsigned)l3 << 16);
            lv.z = (unsigned)l4 | ((unsigned)l5 << 16);
            lv.w = (unsigned)l6 | ((unsigned)l7 << 16);
            *(uint4*)&Ash[l * 136 + sl * 8] = hv;
            *(uint4*)&Asl[l * 136 + sl * 8] = lv;
        }
    }
    __syncthreads();

    // ---- phase 2: GEMM 16 x BN, K=128; A from LDS, B planes from L2
    const int quad = grp;
    const int lr   = sl;
    const int wn0  = wave * (BN / 4);
    f32x4 acc[NT];
#pragma unroll
    for (int nt = 0; nt < NT; nt++) acc[nt] = (f32x4){0.f, 0.f, 0.f, 0.f};

#pragma unroll
    for (int t = 0; t < 4; t++) {
        bf16x8 ah = *(const bf16x8*)&Ash[lr * 136 + t * 32 + quad * 8];
        bf16x8 av = *(const bf16x8*)&Asl[lr * 136 + t * 32 + quad * 8];
        bf16x8 bh[NT], bv[NT];
#pragma unroll
        for (int nt = 0; nt < NT; nt++) {
            long off = ((long)(t * 4 + quad) * NP + wn0 + nt * 16 + lr) * 8;
            bh[nt] = *(const bf16x8*)&Bh[off];
            bv[nt] = *(const bf16x8*)&Bl[off];
        }
#pragma unroll
        for (int nt = 0; nt < NT; nt++) {
            acc[nt] = __builtin_amdgcn_mfma_f32_16x16x32_bf16(ah, bh[nt], acc[nt], 0, 0, 0);
            acc[nt] = __builtin_amdgcn_mfma_f32_16x16x32_bf16(av, bh[nt], acc[nt], 0, 0, 0);
            acc[nt] = __builtin_amdgcn_mfma_f32_16x16x32_bf16(ah, bv[nt], acc[nt], 0, 0, 0);
        }
    }

#pragma unroll
    for (int nt = 0; nt < NT; nt++) {
        const int gc = wn0 + nt * 16 + lr;
#pragma unroll
        for (int r = 0; r < 4; r++) {
            const int gr = blockIdx.x * 16 + quad * 4 + r;
            if (CMODE == 1) {
                oh[(long)gr * 128 + gc] = f2bf(acc[nt][r] * rs_out[gr]);
            } else {
                if (gc < C) outf[(long)gr * C + gc] = acc[nt][r] + bias2[gc];
            }
        }
    }
}

// ---------------------------------------------------------------- launch
extern "C" void kernel_launch(void* const* d_in, const int* in_sizes, int n_in,
                              void* d_out, int out_size, void* d_ws, size_t ws_size,
                              hipStream_t stream) {
    const float* n_feats = (const float*)d_in[0];
    const int*   src     = (const int*)d_in[1];
    const int*   dst     = (const int*)d_in[2];
    const float* Wp      = (const float*)d_in[3];
    const float* bp      = (const float*)d_in[4];
    const float* W1      = (const float*)d_in[5];
    const float* b1      = (const float*)d_in[6];
    const float* W2      = (const float*)d_in[7];
    const float* b2      = (const float*)d_in[8];
    const float* Wc      = (const float*)d_in[9];
    const float* bc      = (const float*)d_in[10];
    float* out = (float*)d_out;
    const int E = in_sizes[1];

    const long PSZ = (long)NRG * CHP * RSZ;    // partials: 1,638,400 u16 (3.28 MB)
    const long NPL = (long)GBK * 8 * 2048;     // n_feats-plane elems (K=256 layout)

    // workspace layout (~90 MB of 256 MiB)
    char* ws = (char*)d_ws;
    unsigned short* hbuf  = (unsigned short*)ws;                    // NN*H bf16
    unsigned short* hbuf2 = hbuf + (long)NN * H;                    // NN*H bf16
    unsigned short* nfh   = hbuf2 + (long)NN * H;                   // NPL
    unsigned short* nfl   = nfh + NPL;
    unsigned short* bt_ph = nfl + NPL;                              // 8*4*128*8
    unsigned short* bt_pl = bt_ph + 32768;
    unsigned short* bt_1h = bt_pl + 32768;                          // 4*4*128*8
    unsigned short* bt_1l = bt_1h + 16384;
    unsigned short* bt_2h = bt_1l + 16384;
    unsigned short* bt_2l = bt_2h + 16384;
    unsigned short* bt_ch = bt_2l + 16384;                          // 4*4*64*8
    unsigned short* bt_cl = bt_ch + 8192;
    int*   cnt_in     = (int*)(bt_cl + 8192);                       // N
    int*   row_start  = cnt_in + NN;                                // N (within-block excl)
    float* rs_out     = (float*)(row_start + NN);                   // N
    float* rs_in      = rs_out + NN;                                // N
    int*   block_sums = (int*)(rs_in + NN);                         // 256
    unsigned short* p_out = (unsigned short*)(block_sums + 256);    // PSZ u16
    unsigned short* p_in  = p_out + PSZ;                            // PSZ u16
    int*   csr_src    = (int*)(p_in + PSZ);                         // E

    const int NB = (NN + 255) / 256;    // 196
    const int AB = NN / 16;             // 3125 fused agg+GEMM blocks

    // D1: histograms (256, XCD-pinned) + weight prep (72) + n_feats split (782)
    hist_prep<<<NRG * CHP + 72 + GBK, 1024, 0, stream>>>(
        src, dst, p_out, p_in, E, Wp, W1, W2, Wc,
        bt_ph, bt_pl, bt_1h, bt_1l, bt_2h, bt_2l, bt_ch, bt_cl,
        n_feats, nfh, nfl);
    // D2: merge+scan (196) + FUSED proj+layer1 GEMM (782):
    //     hbuf = bf16(((n_feats@Wp + bp) @ W1) * rs_out)
    merge_proj_l1<<<NB + GBK, 256, 0, stream>>>(
        p_out, p_in, cnt_in, rs_out, rs_in, row_start, block_sums, NN, NB,
        nfh, nfl, bt_ph, bt_pl, bp, bt_1h, bt_1l, hbuf, NN);
    // D3: scan of block sums (1 block)
    scansums<<<1, 256, 0, stream>>>(block_sums, NB);
    // D4: CSR fill (no global atomics), 1024 threads
    fill_csr_part<<<dim3(NRG, CHP), 1024, 0, stream>>>(
        src, dst, row_start, block_sums, p_in, csr_src, E, NN);
    // D5: fused aggregate-1 + layer-2 GEMM: hbuf2 = bf16((relu(rs_in*(A hbuf)+b1) @ W2)*rs_out)
    agg_gemm<1><<<AB, 256, 0, stream>>>(
        (const uint4*)hbuf, csr_src, row_start, block_sums, cnt_in, rs_in, b1,
        bt_2h, bt_2l, rs_out, nullptr, hbuf2, nullptr);
    // D6: fused aggregate-2 + classifier: out = relu(rs_in*(A hbuf2)+b2) @ Wc + bc
    agg_gemm<0><<<AB, 256, 0, stream>>>(
        (const uint4*)hbuf2, csr_src, row_start, block_sums, cnt_in, rs_in, b2,
        bt_ch, bt_cl, nullptr, bc, nullptr, out);
}